// Round 6
// baseline (803.571 us; speedup 1.0000x reference)
//
#include <hip/hip_runtime.h>
#include <hip/hip_bf16.h>
#include <stdint.h>

// Problem constants (from reference)
#define M_DIM 8192              // 4*2048 batch*seq rows
#define N_DIM 4096              // out_features
#define K_DIM 4096              // in_features
#define NOG   4096              // num out groups (out_group=1)
#define NIG   512               // num in groups (in_group=8)

typedef __bf16 bf16;
typedef __attribute__((ext_vector_type(8))) __bf16 bf16x8;   // 4 VGPRs — MFMA A/B frag
typedef __attribute__((ext_vector_type(4))) float f32x4;     // MFMA C/D frag

// Tiled bf16 layout for the B (weight) operand ("chunk order"):
//   tile(g, h) = rows [g*16,(g+1)*16) x cols [h*32,(h+1)*32)
//   stored as 64 consecutive 16-B chunks, chunk index c = kblk*16 + row
//   global chunk id = (g * 128 + h) * 64 + kblk * 16 + row.
// GEMM B-staging reads 1024 CONTIGUOUS bytes per gload16 (lane l -> chunk l)
// and LDS receives fragment-read order -> zero bank conflicts (measured 0).
// The A operand is now consumed DIRECTLY from fp32 (conversion fused into
// the GEMM's staging) — the separate convert pass (201 MB of traffic + 67 MB
// GEMM re-read + one kernel dispatch) is eliminated.

// ---------------------------------------------------------------------------
// async global->LDS, 16 B per lane. LDS dest is wave-uniform base + lane*16.
__device__ __forceinline__ void gload16(const void* g, void* lds) {
    __builtin_amdgcn_global_load_lds(
        (__attribute__((address_space(1))) void*)g,
        (__attribute__((address_space(3))) void*)lds,
        16 /*size*/, 0 /*offset*/, 0 /*aux*/);
}

// ---------------------------------------------------------------------------
// Kernel 1: AQLM dequant into chunk-order tiles (grid-stride streamer).
// Chunk id decode: r=id&15, kblk=(id>>4)&3, h=(id>>6)&127, g=id>>13;
// out-feature o = g*16+r, in-group iG = h*4+kblk. Per chunk: one 4-B code,
// one 4-B scale, one 32-B codebook gather (2 MB table -> L2-resident), one
// coalesced 16-B store.
__global__ __launch_bounds__(256) void k_dequant(const int* __restrict__ codes,
                                                 const float* __restrict__ cb,
                                                 const float* __restrict__ scales,
                                                 bf16* __restrict__ w) {
    const int total  = NOG * (K_DIM / 8);                // 2,097,152 chunks
    const int stride = gridDim.x * 256;
    for (int id = blockIdx.x * 256 + threadIdx.x; id < total; id += stride) {
        const int r    = id & 15;
        const int kblk = (id >> 4) & 3;
        const int h    = (id >> 6) & 127;
        const int g    = id >> 13;
        const int o    = g * 16 + r;
        const int iG   = h * 4 + kblk;
        const unsigned code = (unsigned)codes[o * NIG + iG];
        const float s = scales[o];
        const float4* e = (const float4*)(cb + (size_t)code * 8);
        float4 e0 = e[0], e1 = e[1];
        bf16x8 v;
        v[0] = (bf16)(e0.x * s); v[1] = (bf16)(e0.y * s);
        v[2] = (bf16)(e0.z * s); v[3] = (bf16)(e0.w * s);
        v[4] = (bf16)(e1.x * s); v[5] = (bf16)(e1.y * s);
        v[6] = (bf16)(e1.z * s); v[7] = (bf16)(e1.w * s);
        ((bf16x8*)w)[id] = v;
    }
}

// ---------------------------------------------------------------------------
// Kernel 2: C[m,n] = sum_k A32[m,k]*B[n,k] + bias[n], A fp32 row-major,
// B chunk-order bf16. Structure = round-0 proven GEMM (239.8 us, MfmaUtil
// 50.5; 48 KB LDS -> 2 blocks/CU, m114 inter-block overlap). Only the
// A-staging changed: reg-stage fp32 -> in-register bf16 convert ->
// ds_write_b128 in the SAME chunk-order LDS layout (fragment reads and
// MFMA schedule byte-identical to round 0).
//   Per wave per K-step: 16x float4 loads (lane l covers chunk l of each
//   group-half: row=l&15, kblk=(l>>4)&3 -> 2x16B at +0,+16 and +128,+144
//   bytes), 16 cvt pairs, 8 ds_write_b128. Lanes {l,l+16,l+32,l+48} share
//   each 128-B line -> full line utilization across the 2 loads.
// Deeper-pipelined 1-block/CU schedules measured SLOWER (rounds 2-4:
// 245.7 / 281.5 / 260.8) — do not re-attempt.
#define BM 256
#define BN 128
#define BK 64
#define KSTEPS (K_DIM / BK)

__global__ __launch_bounds__(256, 2) void k_gemm_fused(
    const float* __restrict__ A32,   // [M_DIM, K_DIM] fp32 row-major
    const bf16* __restrict__ B,      // chunk-order tiled [256 groups][128 halves]
    const float* __restrict__ bias,  // [N_DIM]
    float* __restrict__ C)           // [M_DIM, N_DIM] row-major
{
    // LDS: per group-half 512 elems (64 chunks); As = 16 groups x 2 halves.
    __shared__ __align__(16) bf16 As[BM * BK];   // 32 KB
    __shared__ __align__(16) bf16 Bs[BN * BK];   // 16 KB

    const int tid  = threadIdx.x;
    const int wave = tid >> 6;         // 0..3
    const int lane = tid & 63;
    const int quad = lane >> 4;        // 0..3 (= kblk for staging)
    const int l16  = lane & 15;        // (= row-in-group for staging)

    const int bn0 = blockIdx.x * BN;
    const int bm0 = blockIdx.y * BM;
    const int wm = (wave >> 1) * 128;  // wave's 128x64 subtile
    const int wn = (wave & 1) * 64;

    // A staging sources (fp32): lane l covers chunk l of each group-half.
    const float* pAf[4];
    #pragma unroll
    for (int gi = 0; gi < 4; ++gi) {
        const int G = blockIdx.y * 16 + wave * 4 + gi;     // A group (16 rows)
        pAf[gi] = A32 + (size_t)(G * 16 + l16) * K_DIM + quad * 8;
    }
    // B staging sources: lane l fetches chunk l of each group-half tile.
    const bf16* pB[2];
    #pragma unroll
    for (int gi = 0; gi < 2; ++gi) {
        const int g = blockIdx.x * 8 + wave * 2 + gi;      // B group
        pB[gi] = B + ((size_t)g * 8192 + lane) * 8;
    }
    bf16* AsW = As + wave * 4096;      // wave's 4 A-groups (4*2*512 elems)
    bf16* BsW = Bs + wave * 2048;      // wave's 2 B-groups

    const int gA0 = (wave >> 1) * 8;   // first A group this wave reads
    const int gB0 = (wave & 1) * 4;    // first B group

    f32x4 acc[8][4] = {};

    for (int ks = 0; ks < KSTEPS; ++ks) {
        // ---- B staging: async global->LDS (unchanged) ----
        #pragma unroll
        for (int gi = 0; gi < 2; ++gi) {
            gload16(pB[gi],       BsW + gi * 1024);
            gload16(pB[gi] + 512, BsW + gi * 1024 + 512);
            pB[gi] += 1024;
        }
        // ---- A staging: fp32 load -> bf16 convert -> chunk-order ds_write ----
        #pragma unroll
        for (int gi = 0; gi < 4; ++gi) {
            const float* pa = pAf[gi] + ks * 64;
            float4 f0 = *(const float4*)(pa);         // h0 chunk, first 4
            float4 f1 = *(const float4*)(pa + 4);     // h0 chunk, last 4
            float4 f2 = *(const float4*)(pa + 32);    // h1 chunk, first 4
            float4 f3 = *(const float4*)(pa + 36);    // h1 chunk, last 4
            bf16x8 c0, c1;
            c0[0] = (bf16)f0.x; c0[1] = (bf16)f0.y; c0[2] = (bf16)f0.z; c0[3] = (bf16)f0.w;
            c0[4] = (bf16)f1.x; c0[5] = (bf16)f1.y; c0[6] = (bf16)f1.z; c0[7] = (bf16)f1.w;
            c1[0] = (bf16)f2.x; c1[1] = (bf16)f2.y; c1[2] = (bf16)f2.z; c1[3] = (bf16)f2.w;
            c1[4] = (bf16)f3.x; c1[5] = (bf16)f3.y; c1[6] = (bf16)f3.z; c1[7] = (bf16)f3.w;
            ((bf16x8*)AsW)[gi * 128 + lane]      = c0;   // half 0, chunk=lane
            ((bf16x8*)AsW)[gi * 128 + 64 + lane] = c1;   // half 1, chunk=lane
        }
        __syncthreads();   // drains vmcnt + lgkmcnt -> staged data visible

        // Fragment reads: 64 consecutive chunks per read -> conflict-free.
        // Lane's elems: A[m = l16][k = quad*8..+8] of (group, half).
        bf16x8 af0[8], af1[8], bq0[4], bq1[4];
        #pragma unroll
        for (int t = 0; t < 8; ++t) {
            af0[t] = *(const bf16x8*)(As + (size_t)(gA0 + t) * 1024 + lane * 8);
            af1[t] = *(const bf16x8*)(As + (size_t)(gA0 + t) * 1024 + 512 + lane * 8);
        }
        #pragma unroll
        for (int t = 0; t < 4; ++t) {
            bq0[t] = *(const bf16x8*)(Bs + (size_t)(gB0 + t) * 1024 + lane * 8);
            bq1[t] = *(const bf16x8*)(Bs + (size_t)(gB0 + t) * 1024 + 512 + lane * 8);
        }

        #pragma unroll
        for (int i = 0; i < 8; ++i)
            #pragma unroll
            for (int j = 0; j < 4; ++j)
                acc[i][j] = __builtin_amdgcn_mfma_f32_16x16x32_bf16(
                    af0[i], bq0[j], acc[i][j], 0, 0, 0);
        #pragma unroll
        for (int i = 0; i < 8; ++i)
            #pragma unroll
            for (int j = 0; j < 4; ++j)
                acc[i][j] = __builtin_amdgcn_mfma_f32_16x16x32_bf16(
                    af1[i], bq1[j], acc[i][j], 0, 0, 0);

        __syncthreads();   // all reads done before next overwrite
    }

    // Epilogue: C/D layout col = lane&15, row = quad*4 + reg  [m89/m91-verified]
    #pragma unroll
    for (int j = 0; j < 4; ++j) {
        const int gn = bn0 + wn + j * 16 + l16;
        const float bz = bias[gn];
        #pragma unroll
        for (int i = 0; i < 8; ++i) {
            float* cp = C + (size_t)(bm0 + wm + i * 16 + quad * 4) * N_DIM + gn;
            #pragma unroll
            for (int r = 0; r < 4; ++r)
                cp[(size_t)r * N_DIM] = acc[i][j][r] + bz;
        }
    }
}

// ---------------------------------------------------------------------------
extern "C" void kernel_launch(void* const* d_in, const int* in_sizes, int n_in,
                              void* d_out, int out_size, void* d_ws, size_t ws_size,
                              hipStream_t stream) {
    const float* input     = (const float*)d_in[0];   // [4,2048,4096]
    const int*   codes     = (const int*)d_in[1];     // [4096,512,1]
    const float* codebooks = (const float*)d_in[2];   // [1,65536,1,8]
    const float* scales    = (const float*)d_in[3];   // [4096]
    const float* bias      = (const float*)d_in[4];   // [4096]
    float* out = (float*)d_out;                        // [4,2048,4096]

    // Workspace: only W_tiled (33.5 MB) now; fully written by dequant before
    // the GEMM reads it, so the 0xAA poison is irrelevant.
    bf16* Wbf = (bf16*)d_ws;

    (void)in_sizes; (void)n_in; (void)out_size; (void)ws_size;

    // 1) dequantize W -> bf16, chunk-order tiled (grid-stride streamer).
    k_dequant<<<dim3(2048), 256, 0, stream>>>(codes, codebooks, scales, Wbf);

    // 2) fused convert+GEMM: reads fp32 activations directly.
    {
        dim3 g(N_DIM / BN, M_DIM / BM);   // (32, 32)
        k_gemm_fused<<<g, 256, 0, stream>>>(input, Wbf, bias, out);
    }
}